// Round 1
// baseline (1037.214 us; speedup 1.0000x reference)
//
#include <hip/hip_runtime.h>
#include <math.h>

#define N 2048
#define CX 768
#define CS 384
#define H 16
#define DH 48
#define BQ 32
#define BKT 64

__device__ inline float waveReduceSum(float v){
  #pragma unroll
  for(int o=32;o>0;o>>=1) v += __shfl_xor(v,o);
  return v;
}

// ---------------- LayerNorm of x (no affine) ----------------
__global__ __launch_bounds__(256) void ln_x_kernel(const float* __restrict__ x,
                                                   float* __restrict__ xn){
  int row = blockIdx.x;
  int t = threadIdx.x;
  const float* xr = x + (size_t)row*CX;
  float v0 = xr[t], v1 = xr[t+256], v2 = xr[t+512];
  float s = v0+v1+v2;
  __shared__ float red[4], red2[4];
  s = waveReduceSum(s);
  if((t&63)==0) red[t>>6] = s;
  __syncthreads();
  float mu = (red[0]+red[1]+red[2]+red[3]) * (1.0f/CX);
  float d0=v0-mu, d1=v1-mu, d2=v2-mu;
  float q = d0*d0+d1*d1+d2*d2;
  q = waveReduceSum(q);
  if((t&63)==0) red2[t>>6] = q;
  __syncthreads();
  float var = (red2[0]+red2[1]+red2[2]+red2[3]) * (1.0f/CX);
  float r = rsqrtf(var + 1e-5f);
  float* o = xn + (size_t)row*CX;
  o[t] = d0*r; o[t+256] = d1*r; o[t+512] = d2*r;
}

// ---------------- LayerNorm of single_cond (weight only) ----------------
__global__ __launch_bounds__(128) void ln_sc_kernel(const float* __restrict__ scin,
                                                    const float* __restrict__ w,
                                                    float* __restrict__ sc){
  int row = blockIdx.x;
  int t = threadIdx.x;
  const float* xr = scin + (size_t)row*CS;
  float v0 = xr[t], v1 = xr[t+128], v2 = xr[t+256];
  float s = v0+v1+v2;
  __shared__ float red[2], red2[2];
  s = waveReduceSum(s);
  if((t&63)==0) red[t>>6] = s;
  __syncthreads();
  float mu = (red[0]+red[1]) * (1.0f/CS);
  float d0=v0-mu, d1=v1-mu, d2=v2-mu;
  float q = d0*d0+d1*d1+d2*d2;
  q = waveReduceSum(q);
  if((t&63)==0) red2[t>>6] = q;
  __syncthreads();
  float var = (red2[0]+red2[1]) * (1.0f/CS);
  float r = rsqrtf(var + 1e-5f);
  float* o = sc + (size_t)row*CS;
  o[t]     = d0*r*w[t];
  o[t+128] = d1*r*w[t+128];
  o[t+256] = d2*r*w[t+256];
}

// ---------------- Generic fp32 GEMM: C(MxCX) = A(MxK) @ B(KxCX), epilogue modes ----
// MODE bits: 1 = add bias[col], 2 = sigmoid, 4 = multiply by mul[row,col]
#define BMg 64
#define BNg 64
#define BKg 16
#define LDP 68

template<int K, int MODE>
__global__ __launch_bounds__(256) void gemm_kernel(const float* __restrict__ A,
    const float* __restrict__ B, const float* __restrict__ bias,
    const float* __restrict__ mul, float* __restrict__ C){
  __shared__ float Ast[BKg][LDP];   // transposed A tile
  __shared__ float Bs[BKg][LDP];
  int tid = threadIdx.x;
  int r0 = blockIdx.y * BMg;
  int c0 = blockIdx.x * BNg;
  int tx = tid & 15, ty = tid >> 4;
  int la_row = tid >> 2;
  int la_k   = (tid & 3) * 4;
  int lb_row = tid >> 4;
  int lb_c   = (tid & 15) * 4;
  float acc[4][4] = {};
  for(int k0=0;k0<K;k0+=BKg){
    float4 av = *(const float4*)(A + (size_t)(r0+la_row)*K + k0 + la_k);
    float4 bv = *(const float4*)(B + (size_t)(k0+lb_row)*CX + c0 + lb_c);
    __syncthreads();
    Ast[la_k+0][la_row]=av.x; Ast[la_k+1][la_row]=av.y;
    Ast[la_k+2][la_row]=av.z; Ast[la_k+3][la_row]=av.w;
    *(float4*)&Bs[lb_row][lb_c] = bv;
    __syncthreads();
    #pragma unroll
    for(int kk=0;kk<BKg;kk++){
      float4 a = *(const float4*)&Ast[kk][ty*4];
      float4 b = *(const float4*)&Bs[kk][tx*4];
      acc[0][0]+=a.x*b.x; acc[0][1]+=a.x*b.y; acc[0][2]+=a.x*b.z; acc[0][3]+=a.x*b.w;
      acc[1][0]+=a.y*b.x; acc[1][1]+=a.y*b.y; acc[1][2]+=a.y*b.z; acc[1][3]+=a.y*b.w;
      acc[2][0]+=a.z*b.x; acc[2][1]+=a.z*b.y; acc[2][2]+=a.z*b.z; acc[2][3]+=a.z*b.w;
      acc[3][0]+=a.w*b.x; acc[3][1]+=a.w*b.y; acc[3][2]+=a.w*b.z; acc[3][3]+=a.w*b.w;
    }
  }
  #pragma unroll
  for(int i=0;i<4;i++){
    int row = r0 + ty*4 + i;
    #pragma unroll
    for(int j=0;j<4;j++){
      int col = c0 + tx*4 + j;
      float v = acc[i][j];
      if(MODE & 1) v += bias[col];
      if(MODE & 2) v = 1.0f/(1.0f + expf(-v));
      if(MODE & 4) v *= mul[(size_t)row*CX + col];
      C[(size_t)row*CX + col] = v;
    }
  }
}

// ---------------- AdaptiveLayerNorm fused dual GEMM ----------------
// xa = sigmoid(sc@Ws + bs) * xn + sc@Wb
__global__ __launch_bounds__(256) void adaln_kernel(const float* __restrict__ scb,
    const float* __restrict__ Ws, const float* __restrict__ bs,
    const float* __restrict__ Wb, const float* __restrict__ xn,
    float* __restrict__ xa){
  __shared__ float Ast[BKg][LDP];
  __shared__ float Bs1[BKg][LDP];
  __shared__ float Bs2[BKg][LDP];
  int tid = threadIdx.x;
  int r0 = blockIdx.y * BMg;
  int c0 = blockIdx.x * BNg;
  int tx = tid & 15, ty = tid >> 4;
  int la_row = tid >> 2;
  int la_k   = (tid & 3) * 4;
  int lb_row = tid >> 4;
  int lb_c   = (tid & 15) * 4;
  float acc1[4][4] = {};
  float acc2[4][4] = {};
  for(int k0=0;k0<CS;k0+=BKg){
    float4 av = *(const float4*)(scb + (size_t)(r0+la_row)*CS + k0 + la_k);
    float4 b1 = *(const float4*)(Ws + (size_t)(k0+lb_row)*CX + c0 + lb_c);
    float4 b2 = *(const float4*)(Wb + (size_t)(k0+lb_row)*CX + c0 + lb_c);
    __syncthreads();
    Ast[la_k+0][la_row]=av.x; Ast[la_k+1][la_row]=av.y;
    Ast[la_k+2][la_row]=av.z; Ast[la_k+3][la_row]=av.w;
    *(float4*)&Bs1[lb_row][lb_c] = b1;
    *(float4*)&Bs2[lb_row][lb_c] = b2;
    __syncthreads();
    #pragma unroll
    for(int kk=0;kk<BKg;kk++){
      float4 a  = *(const float4*)&Ast[kk][ty*4];
      float4 b1v = *(const float4*)&Bs1[kk][tx*4];
      float4 b2v = *(const float4*)&Bs2[kk][tx*4];
      acc1[0][0]+=a.x*b1v.x; acc1[0][1]+=a.x*b1v.y; acc1[0][2]+=a.x*b1v.z; acc1[0][3]+=a.x*b1v.w;
      acc1[1][0]+=a.y*b1v.x; acc1[1][1]+=a.y*b1v.y; acc1[1][2]+=a.y*b1v.z; acc1[1][3]+=a.y*b1v.w;
      acc1[2][0]+=a.z*b1v.x; acc1[2][1]+=a.z*b1v.y; acc1[2][2]+=a.z*b1v.z; acc1[2][3]+=a.z*b1v.w;
      acc1[3][0]+=a.w*b1v.x; acc1[3][1]+=a.w*b1v.y; acc1[3][2]+=a.w*b1v.z; acc1[3][3]+=a.w*b1v.w;
      acc2[0][0]+=a.x*b2v.x; acc2[0][1]+=a.x*b2v.y; acc2[0][2]+=a.x*b2v.z; acc2[0][3]+=a.x*b2v.w;
      acc2[1][0]+=a.y*b2v.x; acc2[1][1]+=a.y*b2v.y; acc2[1][2]+=a.y*b2v.z; acc2[1][3]+=a.y*b2v.w;
      acc2[2][0]+=a.z*b2v.x; acc2[2][1]+=a.z*b2v.y; acc2[2][2]+=a.z*b2v.z; acc2[2][3]+=a.z*b2v.w;
      acc2[3][0]+=a.w*b2v.x; acc2[3][1]+=a.w*b2v.y; acc2[3][2]+=a.w*b2v.z; acc2[3][3]+=a.w*b2v.w;
    }
  }
  #pragma unroll
  for(int i=0;i<4;i++){
    int row = r0 + ty*4 + i;
    #pragma unroll
    for(int j=0;j<4;j++){
      int col = c0 + tx*4 + j;
      float g = 1.0f/(1.0f + expf(-(acc1[i][j] + bs[col])));
      xa[(size_t)row*CX + col] = g * xn[(size_t)row*CX + col] + acc2[i][j];
    }
  }
}

// ---------------- Flash attention per (head, 32-query tile) ----------------
// logits = (q*scale)·k + pair; mask -> -1e9; softmax; O = P@V; O *= gate (pre-sigmoided)
__global__ __launch_bounds__(256) void attn_kernel(const float* __restrict__ qg,
    const float* __restrict__ kg, const float* __restrict__ vg,
    const float* __restrict__ pair, const int* __restrict__ mask,
    const float* __restrict__ gate, float* __restrict__ wag){
  int h  = blockIdx.y;
  int q0 = blockIdx.x * BQ;
  int tid = threadIdx.x;
  int tx = tid & 15, ty = tid >> 4;
  int ro = tid >> 3;          // PV: output row 0..31
  int dg = (tid & 7) * 6;     // PV: 6 d-columns

  __shared__ float QsT[DH][34];      // [d][row]
  __shared__ float KsT[DH][LDP];     // [d][col]
  __shared__ float Vs[BKT][DH];      // [col][d]
  __shared__ float Ps[BQ][LDP];
  __shared__ float rowm[BQ], rowl[BQ], rowalpha[BQ], tmax[BQ], tsum[BQ];

  const float scale = 0.14433756729740643f; // 48^-0.5

  for(int idx=tid; idx<BQ*DH; idx+=256){
    int r = idx/DH, d = idx%DH;
    QsT[d][r] = qg[(size_t)(q0+r)*CX + h*DH + d] * scale;
  }
  if(tid < BQ){ rowm[tid] = -3e38f; rowl[tid] = 0.0f; }

  float oacc[6] = {0,0,0,0,0,0};

  for(int kt=0; kt<N/BKT; kt++){
    int k0t = kt*BKT;
    __syncthreads();   // prev-iter LDS reads done (also covers Q/stat init)
    #pragma unroll
    for(int it=0; it<3; it++){
      int f4i = tid + it*256;                  // 0..767
      int c = f4i/12, dd = (f4i%12)*4;
      float4 kv4 = *(const float4*)(kg + (size_t)(k0t+c)*CX + h*DH + dd);
      KsT[dd+0][c]=kv4.x; KsT[dd+1][c]=kv4.y; KsT[dd+2][c]=kv4.z; KsT[dd+3][c]=kv4.w;
      *(float4*)&Vs[c][dd] = *(const float4*)(vg + (size_t)(k0t+c)*CX + h*DH + dd);
    }
    __syncthreads();

    // ---- S = Q K^T (2 rows x 4 cols per thread) ----
    float s00=0,s01=0,s02=0,s03=0,s10=0,s11=0,s12=0,s13=0;
    #pragma unroll 8
    for(int d=0; d<DH; d++){
      float2 qv = *(const float2*)&QsT[d][2*ty];
      float4 kf = *(const float4*)&KsT[d][tx*4];
      s00 += qv.x*kf.x; s01 += qv.x*kf.y; s02 += qv.x*kf.z; s03 += qv.x*kf.w;
      s10 += qv.y*kf.x; s11 += qv.y*kf.y; s12 += qv.y*kf.z; s13 += qv.y*kf.w;
    }
    int4 mv = *(const int4*)(mask + k0t + tx*4);
    const float* pr0 = pair + ((size_t)h*N + (q0+2*ty))*N + k0t + tx*4;
    float4 p0 = *(const float4*)pr0;
    float4 p1 = *(const float4*)(pr0 + N);
    s00 = mv.x ? s00 + p0.x : -1e9f;
    s01 = mv.y ? s01 + p0.y : -1e9f;
    s02 = mv.z ? s02 + p0.z : -1e9f;
    s03 = mv.w ? s03 + p0.w : -1e9f;
    s10 = mv.x ? s10 + p1.x : -1e9f;
    s11 = mv.y ? s11 + p1.y : -1e9f;
    s12 = mv.z ? s12 + p1.z : -1e9f;
    s13 = mv.w ? s13 + p1.w : -1e9f;

    // ---- row max (within 16-lane groups) ----
    float mx0 = fmaxf(fmaxf(s00,s01), fmaxf(s02,s03));
    float mx1 = fmaxf(fmaxf(s10,s11), fmaxf(s12,s13));
    #pragma unroll
    for(int o=1;o<16;o<<=1){
      mx0 = fmaxf(mx0, __shfl_xor(mx0,o));
      mx1 = fmaxf(mx1, __shfl_xor(mx1,o));
    }
    if(tx==0){ tmax[2*ty]=mx0; tmax[2*ty+1]=mx1; }
    __syncthreads();
    if(tid < BQ){
      float mo = rowm[tid];
      float mn = fmaxf(mo, tmax[tid]);
      rowalpha[tid] = expf(mo - mn);
      rowm[tid] = mn;
    }
    __syncthreads();

    // ---- P = exp(S - m), write LDS, row sums ----
    float m0 = rowm[2*ty], m1 = rowm[2*ty+1];
    s00=expf(s00-m0); s01=expf(s01-m0); s02=expf(s02-m0); s03=expf(s03-m0);
    s10=expf(s10-m1); s11=expf(s11-m1); s12=expf(s12-m1); s13=expf(s13-m1);
    *(float4*)&Ps[2*ty  ][tx*4] = make_float4(s00,s01,s02,s03);
    *(float4*)&Ps[2*ty+1][tx*4] = make_float4(s10,s11,s12,s13);
    float rs0 = s00+s01+s02+s03;
    float rs1 = s10+s11+s12+s13;
    #pragma unroll
    for(int o=1;o<16;o<<=1){
      rs0 += __shfl_xor(rs0,o);
      rs1 += __shfl_xor(rs1,o);
    }
    if(tx==0){ tsum[2*ty]=rs0; tsum[2*ty+1]=rs1; }
    __syncthreads();
    if(tid < BQ) rowl[tid] = rowl[tid]*rowalpha[tid] + tsum[tid];

    // ---- O = O*alpha + P @ V ----
    float al = rowalpha[ro];
    #pragma unroll
    for(int i=0;i<6;i++) oacc[i] *= al;
    #pragma unroll 4
    for(int j=0;j<BKT;j+=2){
      float2 pp = *(const float2*)&Ps[ro][j];
      float2 va = *(const float2*)&Vs[j][dg];
      float2 vb = *(const float2*)&Vs[j][dg+2];
      float2 vc = *(const float2*)&Vs[j][dg+4];
      float2 vd = *(const float2*)&Vs[j+1][dg];
      float2 ve = *(const float2*)&Vs[j+1][dg+2];
      float2 vf = *(const float2*)&Vs[j+1][dg+4];
      oacc[0] += pp.x*va.x + pp.y*vd.x;
      oacc[1] += pp.x*va.y + pp.y*vd.y;
      oacc[2] += pp.x*vb.x + pp.y*ve.x;
      oacc[3] += pp.x*vb.y + pp.y*ve.y;
      oacc[4] += pp.x*vc.x + pp.y*vf.x;
      oacc[5] += pp.x*vc.y + pp.y*vf.y;
    }
  }
  __syncthreads();  // rowl final updates visible
  float linv = 1.0f / rowl[ro];
  size_t orow = (size_t)(q0 + ro);
  #pragma unroll
  for(int i=0;i<6;i++){
    int col = h*DH + dg + i;
    float w = oacc[i] * linv;
    w *= gate[orow*CX + col];
    wag[orow*CX + col] = w;
  }
}

extern "C" void kernel_launch(void* const* d_in, const int* in_sizes, int n_in,
                              void* d_out, int out_size, void* d_ws, size_t ws_size,
                              hipStream_t stream) {
  const float* x           = (const float*)d_in[0];
  const int*   mask        = (const int*)  d_in[1];
  const float* pair        = (const float*)d_in[2];
  const float* single_cond = (const float*)d_in[3];
  const float* ln_sc_w     = (const float*)d_in[4];
  const float* sc_scale_w  = (const float*)d_in[5];
  const float* sc_scale_b  = (const float*)d_in[6];
  const float* sc_bias_w   = (const float*)d_in[7];
  const float* q_w         = (const float*)d_in[8];
  const float* q_b         = (const float*)d_in[9];
  const float* k_w         = (const float*)d_in[10];
  const float* v_w         = (const float*)d_in[11];
  const float* gate_w      = (const float*)d_in[12];
  const float* out_w       = (const float*)d_in[13];
  const float* azc_w       = (const float*)d_in[14];
  const float* azc_b       = (const float*)d_in[15];
  float* out = (float*)d_out;

  float* f = (float*)d_ws;
  const size_t NCX = (size_t)N*CX;
  float* xn  = f;             // later reused as wag
  float* xa  = f + 1*NCX;
  float* qb  = f + 2*NCX;
  float* kb  = f + 3*NCX;
  float* vb  = f + 4*NCX;
  float* gb  = f + 5*NCX;
  float* azc = f + 6*NCX;
  float* scb = f + 7*NCX;     // N*CS
  float* wag = xn;

  ln_x_kernel <<<N, 256, 0, stream>>>(x, xn);
  ln_sc_kernel<<<N, 128, 0, stream>>>(single_cond, ln_sc_w, scb);

  dim3 g(CX/BNg, N/BMg);
  adaln_kernel<<<g, 256, 0, stream>>>(scb, sc_scale_w, sc_scale_b, sc_bias_w, xn, xa);
  gemm_kernel<CX,1><<<g, 256, 0, stream>>>(xa, q_w, q_b, nullptr, qb);
  gemm_kernel<CX,0><<<g, 256, 0, stream>>>(xa, k_w, nullptr, nullptr, kb);
  gemm_kernel<CX,0><<<g, 256, 0, stream>>>(xa, v_w, nullptr, nullptr, vb);
  gemm_kernel<CX,2><<<g, 256, 0, stream>>>(xa, gate_w, nullptr, nullptr, gb);
  gemm_kernel<CS,3><<<g, 256, 0, stream>>>(scb, azc_w, azc_b, nullptr, azc);

  dim3 ga(N/BQ, H);
  attn_kernel<<<ga, 256, 0, stream>>>(qb, kb, vb, pair, mask, gb, wag);

  gemm_kernel<CX,4><<<g, 256, 0, stream>>>(wag, out_w, nullptr, azc, out);
}

// Round 2
// 541.142 us; speedup vs baseline: 1.9167x; 1.9167x over previous
//
#include <hip/hip_runtime.h>
#include <math.h>

#define NN 2048
#define CXX 768
#define CSS 384
#define HH 16
#define DHH 48

typedef short bf16x8 __attribute__((ext_vector_type(8)));
typedef float f32x4 __attribute__((ext_vector_type(4)));

#define MFMA16(a,b,c) __builtin_amdgcn_mfma_f32_16x16x32_bf16(a,b,c,0,0,0)

__device__ __forceinline__ unsigned short f2bf(float f){
  unsigned u = __float_as_uint(f);
  u += 0x7FFFu + ((u >> 16) & 1u);
  return (unsigned short)(u >> 16);
}
__device__ __forceinline__ float bf2f(unsigned short u){
  return __uint_as_float(((unsigned)u) << 16);
}
__device__ __forceinline__ void async_copy16(const void* g, void* l){
  __builtin_amdgcn_global_load_lds((const __attribute__((address_space(1))) void*)g,
                                   (__attribute__((address_space(3))) void*)l, 16, 0, 0);
}

__device__ inline float waveReduceSum(float v){
  #pragma unroll
  for(int o=32;o>0;o>>=1) v += __shfl_xor(v,o);
  return v;
}

// ---------------- weight fp32 -> bf16 transpose: W (K x Ncols) -> Wt (Ncols x K) ----
__global__ __launch_bounds__(256) void transpose_bf16(const float* __restrict__ W,
    unsigned short* __restrict__ Wt, int K, int Ncols){
  __shared__ unsigned short t[32][33];
  int n0 = blockIdx.x*32, k0 = blockIdx.y*32;
  int c = threadIdx.x & 31, r = threadIdx.x >> 5;   // r in 0..7
  #pragma unroll
  for(int i=0;i<32;i+=8){
    float v = W[(size_t)(k0 + r + i)*Ncols + n0 + c];
    t[c][r+i] = f2bf(v);
  }
  __syncthreads();
  #pragma unroll
  for(int i=0;i<32;i+=8){
    Wt[(size_t)(n0 + r + i)*K + k0 + c] = t[r+i][c];
  }
}

// ---------------- LayerNorm of x (no affine), fp32 out ----------------
__global__ __launch_bounds__(256) void ln_x_kernel(const float* __restrict__ x,
                                                   float* __restrict__ xn){
  int row = blockIdx.x;
  int t = threadIdx.x;
  const float* xr = x + (size_t)row*CXX;
  float v0 = xr[t], v1 = xr[t+256], v2 = xr[t+512];
  float s = v0+v1+v2;
  __shared__ float red[4], red2[4];
  s = waveReduceSum(s);
  if((t&63)==0) red[t>>6] = s;
  __syncthreads();
  float mu = (red[0]+red[1]+red[2]+red[3]) * (1.0f/CXX);
  float d0=v0-mu, d1=v1-mu, d2=v2-mu;
  float q = d0*d0+d1*d1+d2*d2;
  q = waveReduceSum(q);
  if((t&63)==0) red2[t>>6] = q;
  __syncthreads();
  float var = (red2[0]+red2[1]+red2[2]+red2[3]) * (1.0f/CXX);
  float r = rsqrtf(var + 1e-5f);
  float* o = xn + (size_t)row*CXX;
  o[t] = d0*r; o[t+256] = d1*r; o[t+512] = d2*r;
}

// ---------------- LayerNorm of single_cond (weight only), bf16 out ----------------
__global__ __launch_bounds__(128) void ln_sc_kernel(const float* __restrict__ scin,
                                                    const float* __restrict__ w,
                                                    unsigned short* __restrict__ sc){
  int row = blockIdx.x;
  int t = threadIdx.x;
  const float* xr = scin + (size_t)row*CSS;
  float v0 = xr[t], v1 = xr[t+128], v2 = xr[t+256];
  float s = v0+v1+v2;
  __shared__ float red[2], red2[2];
  s = waveReduceSum(s);
  if((t&63)==0) red[t>>6] = s;
  __syncthreads();
  float mu = (red[0]+red[1]) * (1.0f/CSS);
  float d0=v0-mu, d1=v1-mu, d2=v2-mu;
  float q = d0*d0+d1*d1+d2*d2;
  q = waveReduceSum(q);
  if((t&63)==0) red2[t>>6] = q;
  __syncthreads();
  float var = (red2[0]+red2[1]) * (1.0f/CSS);
  float r = rsqrtf(var + 1e-5f);
  unsigned short* o = sc + (size_t)row*CSS;
  o[t]     = f2bf(d0*r*w[t]);
  o[t+128] = f2bf(d1*r*w[t+128]);
  o[t+256] = f2bf(d2*r*w[t+256]);
}

// ---------------- MFMA GEMM: C(2048 x NC) = A(2048 x K) @ Bt(NC x K)^T ----------------
// MODE 0: qkvg epilogue -> bf16 out (col<768 add bias; col>=2304 sigmoid)
// MODE 1: fp32 out, sigmoid(acc + bias[col])
// MODE 2: fp32 out, acc * mul[row*NC+col]
template<int K, int NC, int MODE>
__global__ __launch_bounds__(256) void gemm_mfma(const unsigned short* __restrict__ A,
    const unsigned short* __restrict__ Bt, const float* __restrict__ bias,
    const float* __restrict__ mul, void* __restrict__ Cp){
  __shared__ unsigned short As[128*32];
  __shared__ unsigned short Bs[128*32];
  const int tid = threadIdx.x;
  const int w = tid>>6, lane = tid&63;
  const int ln15 = lane&15, hi = lane>>4;
  const int wm = w&1, wn = w>>1;
  const int m0 = blockIdx.y*128, n0 = blockIdx.x*128;
  const int lrow = lane>>2, lk = (lane&3)*8;

  f32x4 z = {0.f,0.f,0.f,0.f};
  f32x4 acc[4][4];
  #pragma unroll
  for(int i=0;i<4;i++)
    #pragma unroll
    for(int j=0;j<4;j++) acc[i][j] = z;

  for(int k0=0;k0<K;k0+=32){
    const unsigned short* ga = A + (size_t)(m0 + w*32 + lrow)*K + k0 + lk;
    const unsigned short* gb = Bt + (size_t)(n0 + w*32 + lrow)*K + k0 + lk;
    async_copy16(ga,          &As[w*1024]);
    async_copy16(ga + 16*K,   &As[w*1024 + 512]);
    async_copy16(gb,          &Bs[w*1024]);
    async_copy16(gb + 16*K,   &Bs[w*1024 + 512]);
    __syncthreads();
    bf16x8 af[4], bfr[4];
    #pragma unroll
    for(int i=0;i<4;i++) af[i]  = *(const bf16x8*)&As[(wm*64 + i*16 + ln15)*32 + hi*8];
    #pragma unroll
    for(int j=0;j<4;j++) bfr[j] = *(const bf16x8*)&Bs[(wn*64 + j*16 + ln15)*32 + hi*8];
    #pragma unroll
    for(int i=0;i<4;i++)
      #pragma unroll
      for(int j=0;j<4;j++)
        acc[i][j] = MFMA16(af[i], bfr[j], acc[i][j]);
    __syncthreads();
  }

  #pragma unroll
  for(int i=0;i<4;i++){
    #pragma unroll
    for(int j=0;j<4;j++){
      #pragma unroll
      for(int r=0;r<4;r++){
        int gm = m0 + wm*64 + i*16 + hi*4 + r;
        int gn = n0 + wn*64 + j*16 + ln15;
        float v = acc[i][j][r];
        if constexpr (MODE == 0){
          if(gn < 768) v += bias[gn];
          if(gn >= 2304) v = 1.0f/(1.0f + __expf(-v));
          ((unsigned short*)Cp)[(size_t)gm*NC + gn] = f2bf(v);
        } else if constexpr (MODE == 1){
          v = 1.0f/(1.0f + __expf(-(v + bias[gn])));
          ((float*)Cp)[(size_t)gm*NC + gn] = v;
        } else {
          ((float*)Cp)[(size_t)gm*NC + gn] = v * mul[(size_t)gm*NC + gn];
        }
      }
    }
  }
}

// ---------------- AdaLN dual-GEMM: xa = sigmoid(sc@Ws+bs)*xn + sc@Wb, bf16 out ----
__global__ __launch_bounds__(256) void adaln_mfma(const unsigned short* __restrict__ A,
    const unsigned short* __restrict__ B1, const unsigned short* __restrict__ B2,
    const float* __restrict__ bs, const float* __restrict__ xn,
    unsigned short* __restrict__ xa){
  __shared__ unsigned short As[128*32];
  __shared__ unsigned short Bs1[128*32];
  __shared__ unsigned short Bs2[128*32];
  const int tid = threadIdx.x;
  const int w = tid>>6, lane = tid&63;
  const int ln15 = lane&15, hi = lane>>4;
  const int wm = w&1, wn = w>>1;
  const int m0 = blockIdx.y*128, n0 = blockIdx.x*128;
  const int lrow = lane>>2, lk = (lane&3)*8;

  f32x4 z = {0.f,0.f,0.f,0.f};
  f32x4 acc1[4][4], acc2[4][4];
  #pragma unroll
  for(int i=0;i<4;i++)
    #pragma unroll
    for(int j=0;j<4;j++){ acc1[i][j] = z; acc2[i][j] = z; }

  for(int k0=0;k0<CSS;k0+=32){
    const unsigned short* ga  = A  + (size_t)(m0 + w*32 + lrow)*CSS + k0 + lk;
    const unsigned short* gb1 = B1 + (size_t)(n0 + w*32 + lrow)*CSS + k0 + lk;
    const unsigned short* gb2 = B2 + (size_t)(n0 + w*32 + lrow)*CSS + k0 + lk;
    async_copy16(ga,            &As[w*1024]);
    async_copy16(ga  + 16*CSS,  &As[w*1024 + 512]);
    async_copy16(gb1,           &Bs1[w*1024]);
    async_copy16(gb1 + 16*CSS,  &Bs1[w*1024 + 512]);
    async_copy16(gb2,           &Bs2[w*1024]);
    async_copy16(gb2 + 16*CSS,  &Bs2[w*1024 + 512]);
    __syncthreads();
    bf16x8 af[4], b1f[4], b2f[4];
    #pragma unroll
    for(int i=0;i<4;i++) af[i]  = *(const bf16x8*)&As[(wm*64 + i*16 + ln15)*32 + hi*8];
    #pragma unroll
    for(int j=0;j<4;j++){
      b1f[j] = *(const bf16x8*)&Bs1[(wn*64 + j*16 + ln15)*32 + hi*8];
      b2f[j] = *(const bf16x8*)&Bs2[(wn*64 + j*16 + ln15)*32 + hi*8];
    }
    #pragma unroll
    for(int i=0;i<4;i++)
      #pragma unroll
      for(int j=0;j<4;j++){
        acc1[i][j] = MFMA16(af[i], b1f[j], acc1[i][j]);
        acc2[i][j] = MFMA16(af[i], b2f[j], acc2[i][j]);
      }
    __syncthreads();
  }

  #pragma unroll
  for(int i=0;i<4;i++)
    #pragma unroll
    for(int j=0;j<4;j++)
      #pragma unroll
      for(int r=0;r<4;r++){
        int gm = m0 + wm*64 + i*16 + hi*4 + r;
        int gn = n0 + wn*64 + j*16 + ln15;
        float g = 1.0f/(1.0f + __expf(-(acc1[i][j][r] + bs[gn])));
        float v = g * xn[(size_t)gm*CXX + gn] + acc2[i][j][r];
        xa[(size_t)gm*CXX + gn] = f2bf(v);
      }
}

// ---------------- MFMA flash attention ----------------
// qkvg: (2048 x 3072) bf16: [q | k | v | gate(sigmoided)]
// per block: head h, 64 q rows; loop 64-key tiles; out wag bf16 (2048 x 768)
__global__ __launch_bounds__(256) void attn_mfma(const unsigned short* __restrict__ qkvg,
    const float* __restrict__ pair, const int* __restrict__ mask,
    unsigned short* __restrict__ wag){
  const int h = blockIdx.y;
  const int q0 = blockIdx.x*64;
  const int tid = threadIdx.x;
  const int w = tid>>6, lane = tid&63;
  const int ln15 = lane&15, hi = lane>>4;

  __shared__ unsigned short Qs[64*72];
  __shared__ unsigned short Ks[64*72];
  __shared__ unsigned short VsT[48*72];
  __shared__ unsigned short Ps[4][16*72];

  // zero the d=48..63 padding of Qs/Ks (read by K-dim of MFMA)
  for(int idx=tid; idx<64*16; idx+=256){
    int row = idx>>4, d = 48 + (idx&15);
    Qs[row*72 + d] = 0;
    Ks[row*72 + d] = 0;
  }
  // stage Q (bf16, 8B vector loads)
  for(int idx=tid; idx<64*12; idx+=256){
    int qr = idx&63, d0 = (idx>>6)*4;
    ushort4 v = *(const ushort4*)&qkvg[(size_t)(q0+qr)*3072 + h*DHH + d0];
    *(ushort4*)&Qs[qr*72 + d0] = v;
  }
  __syncthreads();

  bf16x8 aq0 = *(const bf16x8*)&Qs[(w*16+ln15)*72 + hi*8];
  bf16x8 aq1 = *(const bf16x8*)&Qs[(w*16+ln15)*72 + 32 + hi*8];

  f32x4 z = {0.f,0.f,0.f,0.f};
  f32x4 oacc[3] = {z,z,z};
  float mold[4] = {-1e30f,-1e30f,-1e30f,-1e30f};
  float l[4] = {0.f,0.f,0.f,0.f};
  const float scale = 0.14433756729740643f;
  const int qrb = w*16 + hi*4;

  for(int kt=0; kt<NN/64; ++kt){
    int k0 = kt*64;
    __syncthreads();    // previous tile's LDS reads complete
    for(int idx=tid; idx<64*12; idx+=256){
      int key = idx&63, d0 = (idx>>6)*4;
      ushort4 kv = *(const ushort4*)&qkvg[(size_t)(k0+key)*3072 +  768 + h*DHH + d0];
      *(ushort4*)&Ks[key*72 + d0] = kv;
      ushort4 vv = *(const ushort4*)&qkvg[(size_t)(k0+key)*3072 + 1536 + h*DHH + d0];
      VsT[(d0+0)*72 + key] = vv.x;
      VsT[(d0+1)*72 + key] = vv.y;
      VsT[(d0+2)*72 + key] = vv.z;
      VsT[(d0+3)*72 + key] = vv.w;
    }
    __syncthreads();

    // mask + pair loads first (overlap with MFMA)
    int msk[4];
    float pr[4][4];
    #pragma unroll
    for(int jt=0;jt<4;jt++) msk[jt] = mask[k0 + jt*16 + ln15];
    const float* pb = pair + ((size_t)h*NN + (size_t)(q0+qrb))*NN + k0 + ln15;
    #pragma unroll
    for(int r=0;r<4;r++)
      #pragma unroll
      for(int jt=0;jt<4;jt++)
        pr[jt][r] = pb[(size_t)r*NN + jt*16];

    // S = Q K^T
    f32x4 sreg[4];
    #pragma unroll
    for(int jt=0;jt<4;jt++){
      bf16x8 bk0 = *(const bf16x8*)&Ks[(jt*16+ln15)*72 + hi*8];
      bf16x8 bk1 = *(const bf16x8*)&Ks[(jt*16+ln15)*72 + 32 + hi*8];
      f32x4 s = z;
      s = MFMA16(aq0, bk0, s);
      s = MFMA16(aq1, bk1, s);
      sreg[jt] = s;
    }

    float sv[4][4];
    #pragma unroll
    for(int jt=0;jt<4;jt++)
      #pragma unroll
      for(int r=0;r<4;r++)
        sv[jt][r] = msk[jt] ? sreg[jt][r]*scale + pr[jt][r] : -1e9f;

    // online softmax (rows live in 16-lane groups; redundant per-lane stats)
    float mr[4], al[4], rs[4];
    #pragma unroll
    for(int r=0;r<4;r++)
      mr[r] = fmaxf(fmaxf(sv[0][r],sv[1][r]), fmaxf(sv[2][r],sv[3][r]));
    #pragma unroll
    for(int o=1;o<16;o<<=1)
      #pragma unroll
      for(int r=0;r<4;r++) mr[r] = fmaxf(mr[r], __shfl_xor(mr[r],o));
    #pragma unroll
    for(int r=0;r<4;r++){
      float mn = fmaxf(mold[r], mr[r]);
      al[r] = __expf(mold[r] - mn);
      mold[r] = mn;
    }
    float pv[4][4];
    #pragma unroll
    for(int jt=0;jt<4;jt++)
      #pragma unroll
      for(int r=0;r<4;r++)
        pv[jt][r] = __expf(sv[jt][r] - mold[r]);
    #pragma unroll
    for(int r=0;r<4;r++) rs[r] = pv[0][r]+pv[1][r]+pv[2][r]+pv[3][r];
    #pragma unroll
    for(int o=1;o<16;o<<=1)
      #pragma unroll
      for(int r=0;r<4;r++) rs[r] += __shfl_xor(rs[r],o);
    #pragma unroll
    for(int r=0;r<4;r++) l[r] = l[r]*al[r] + rs[r];

    // write P (bf16) to per-wave LDS, A-frag layout round-trip
    #pragma unroll
    for(int jt=0;jt<4;jt++)
      #pragma unroll
      for(int r=0;r<4;r++)
        Ps[w][(hi*4+r)*72 + jt*16 + ln15] = f2bf(pv[jt][r]);
    __asm__ volatile("s_waitcnt lgkmcnt(0)" ::: "memory");

    #pragma unroll
    for(int dt=0;dt<3;dt++)
      #pragma unroll
      for(int r=0;r<4;r++) oacc[dt][r] *= al[r];

    bf16x8 ap0 = *(const bf16x8*)&Ps[w][ln15*72 + hi*8];
    bf16x8 ap1 = *(const bf16x8*)&Ps[w][ln15*72 + 32 + hi*8];
    #pragma unroll
    for(int dt=0;dt<3;dt++){
      bf16x8 bv0 = *(const bf16x8*)&VsT[(dt*16+ln15)*72 + hi*8];
      bf16x8 bv1 = *(const bf16x8*)&VsT[(dt*16+ln15)*72 + 32 + hi*8];
      oacc[dt] = MFMA16(ap0, bv0, oacc[dt]);
      oacc[dt] = MFMA16(ap1, bv1, oacc[dt]);
    }
  }

  #pragma unroll
  for(int r=0;r<4;r++){
    float linv = 1.0f / l[r];
    int qrow = q0 + qrb + r;
    #pragma unroll
    for(int dt=0;dt<3;dt++){
      int col = h*DHH + dt*16 + ln15;
      float g = bf2f(qkvg[(size_t)qrow*3072 + 2304 + col]);
      float o = oacc[dt][r] * linv * g;
      wag[(size_t)qrow*CXX + col] = f2bf(o);
    }
  }
}

extern "C" void kernel_launch(void* const* d_in, const int* in_sizes, int n_in,
                              void* d_out, int out_size, void* d_ws, size_t ws_size,
                              hipStream_t stream) {
  const float* x           = (const float*)d_in[0];
  const int*   mask        = (const int*)  d_in[1];
  const float* pair        = (const float*)d_in[2];
  const float* single_cond = (const float*)d_in[3];
  const float* ln_sc_w     = (const float*)d_in[4];
  const float* sc_scale_w  = (const float*)d_in[5];
  const float* sc_scale_b  = (const float*)d_in[6];
  const float* sc_bias_w   = (const float*)d_in[7];
  const float* q_w         = (const float*)d_in[8];
  const float* q_b         = (const float*)d_in[9];
  const float* k_w         = (const float*)d_in[10];
  const float* v_w         = (const float*)d_in[11];
  const float* gate_w      = (const float*)d_in[12];
  const float* out_w       = (const float*)d_in[13];
  const float* azc_w       = (const float*)d_in[14];
  const float* azc_b       = (const float*)d_in[15];
  float* out = (float*)d_out;

  unsigned short* p = (unsigned short*)d_ws;
  unsigned short* Wt_scale = p;  p += 768*384;
  unsigned short* Wt_bias  = p;  p += 768*384;
  unsigned short* Wt_azc   = p;  p += 768*384;
  unsigned short* Wt_out   = p;  p += 768*768;
  unsigned short* Wt_qkvg  = p;  p += 3072*768;
  unsigned short* scb      = p;  p += 2048*384;
  unsigned short* xa       = p;  p += 2048*768;
  unsigned short* qkvg     = p;  p += (size_t)2048*3072;
  unsigned short* wag      = p;  p += 2048*768;
  float* fp = (float*)p;
  float* xn  = fp; fp += (size_t)2048*768;
  float* azc = fp;

  // weight prep: fp32 -> bf16, transposed to (N, K)
  dim3 t24_12(24,12), t24_24(24,24);
  transpose_bf16<<<t24_12, 256, 0, stream>>>(sc_scale_w, Wt_scale, 384, 768);
  transpose_bf16<<<t24_12, 256, 0, stream>>>(sc_bias_w,  Wt_bias,  384, 768);
  transpose_bf16<<<t24_12, 256, 0, stream>>>(azc_w,      Wt_azc,   384, 768);
  transpose_bf16<<<t24_24, 256, 0, stream>>>(q_w,    Wt_qkvg + 0*589824, 768, 768);
  transpose_bf16<<<t24_24, 256, 0, stream>>>(k_w,    Wt_qkvg + 1*589824, 768, 768);
  transpose_bf16<<<t24_24, 256, 0, stream>>>(v_w,    Wt_qkvg + 2*589824, 768, 768);
  transpose_bf16<<<t24_24, 256, 0, stream>>>(gate_w, Wt_qkvg + 3*589824, 768, 768);
  transpose_bf16<<<t24_24, 256, 0, stream>>>(out_w,  Wt_out, 768, 768);

  ln_x_kernel <<<NN, 256, 0, stream>>>(x, xn);
  ln_sc_kernel<<<NN, 128, 0, stream>>>(single_cond, ln_sc_w, scb);

  adaln_mfma<<<dim3(6,16), 256, 0, stream>>>(scb, Wt_scale, Wt_bias, sc_scale_b, xn, xa);
  gemm_mfma<768,3072,0><<<dim3(24,16), 256, 0, stream>>>(xa, Wt_qkvg, q_b, nullptr, qkvg);
  gemm_mfma<384,768,1><<<dim3(6,16), 256, 0, stream>>>(scb, Wt_azc, azc_b, nullptr, azc);

  attn_mfma<<<dim3(32,16), 256, 0, stream>>>(qkvg, pair, mask, wag);

  gemm_mfma<768,768,2><<<dim3(6,16), 256, 0, stream>>>(wag, Wt_out, nullptr, azc, out);
}

// Round 3
// 506.508 us; speedup vs baseline: 2.0478x; 1.0684x over previous
//
#include <hip/hip_runtime.h>
#include <math.h>

#define NN 2048
#define CXX 768
#define CSS 384
#define HH 16
#define DHH 48

typedef short bf16x8 __attribute__((ext_vector_type(8)));
typedef float f32x4 __attribute__((ext_vector_type(4)));

#define MFMA16(a,b,c) __builtin_amdgcn_mfma_f32_16x16x32_bf16(a,b,c,0,0,0)

__device__ __forceinline__ unsigned short f2bf(float f){
  unsigned u = __float_as_uint(f);
  u += 0x7FFFu + ((u >> 16) & 1u);
  return (unsigned short)(u >> 16);
}
__device__ __forceinline__ float bf2f(unsigned short u){
  return __uint_as_float(((unsigned)u) << 16);
}
__device__ __forceinline__ void async_copy16(const void* g, void* l){
  __builtin_amdgcn_global_load_lds((const __attribute__((address_space(1))) void*)g,
                                   (__attribute__((address_space(3))) void*)l, 16, 0, 0);
}

__device__ inline float waveReduceSum(float v){
  #pragma unroll
  for(int o=32;o>0;o>>=1) v += __shfl_xor(v,o);
  return v;
}

// ---------------- batched weight fp32 -> bf16 transpose (all 8 matrices) ----------
// z: 0 scale(K384) 1 bias(K384) 2 azc(K384) 3..6 q/k/v/gate(K768) 7 out(K768)
__global__ __launch_bounds__(256) void transpose_all(
    const float* __restrict__ s0, const float* __restrict__ s1, const float* __restrict__ s2,
    const float* __restrict__ s3, const float* __restrict__ s4, const float* __restrict__ s5,
    const float* __restrict__ s6, const float* __restrict__ s7,
    unsigned short* __restrict__ d_scale, unsigned short* __restrict__ d_bias,
    unsigned short* __restrict__ d_azc, unsigned short* __restrict__ d_qkvg,
    unsigned short* __restrict__ d_out){
  int z = blockIdx.z;
  const float* W; unsigned short* Wt; int K;
  switch(z){
    case 0: W=s0; Wt=d_scale; K=384; break;
    case 1: W=s1; Wt=d_bias;  K=384; break;
    case 2: W=s2; Wt=d_azc;   K=384; break;
    case 3: W=s3; Wt=d_qkvg + 0*589824; K=768; break;
    case 4: W=s4; Wt=d_qkvg + 1*589824; K=768; break;
    case 5: W=s5; Wt=d_qkvg + 2*589824; K=768; break;
    case 6: W=s6; Wt=d_qkvg + 3*589824; K=768; break;
    default: W=s7; Wt=d_out; K=768; break;
  }
  int n0 = blockIdx.x*32, k0 = blockIdx.y*32;
  if(k0 >= K) return;
  __shared__ unsigned short t[32][33];
  int c = threadIdx.x & 31, r = threadIdx.x >> 5;
  #pragma unroll
  for(int i=0;i<32;i+=8){
    float v = W[(size_t)(k0 + r + i)*CXX + n0 + c];
    t[c][r+i] = f2bf(v);
  }
  __syncthreads();
  #pragma unroll
  for(int i=0;i<32;i+=8){
    Wt[(size_t)(n0 + r + i)*K + k0 + c] = t[r+i][c];
  }
}

// ---------------- fused LayerNorms: x (fp32 out) + single_cond (bf16 out) ----------
__global__ __launch_bounds__(384) void ln_fused(const float* __restrict__ x,
    const float* __restrict__ scin, const float* __restrict__ w,
    float* __restrict__ xn, unsigned short* __restrict__ scb){
  int row = blockIdx.x;
  int t = threadIdx.x;
  int wid = t>>6, lane = t&63;
  __shared__ float red[6];
  // ---- x LN ----
  float a0 = x[(size_t)row*CXX + t];
  float a1 = x[(size_t)row*CXX + 384 + t];
  float s = waveReduceSum(a0+a1);
  if(lane==0) red[wid]=s;
  __syncthreads();
  float mu = (red[0]+red[1]+red[2]+red[3]+red[4]+red[5]) * (1.0f/CXX);
  float d0=a0-mu, d1=a1-mu;
  float q = waveReduceSum(d0*d0+d1*d1);
  __syncthreads();
  if(lane==0) red[wid]=q;
  __syncthreads();
  float var = (red[0]+red[1]+red[2]+red[3]+red[4]+red[5]) * (1.0f/CXX);
  float r = rsqrtf(var + 1e-5f);
  xn[(size_t)row*CXX + t] = d0*r;
  xn[(size_t)row*CXX + 384 + t] = d1*r;
  // ---- sc LN ----
  float b = scin[(size_t)row*CSS + t];
  float s2 = waveReduceSum(b);
  __syncthreads();
  if(lane==0) red[wid]=s2;
  __syncthreads();
  float mu2 = (red[0]+red[1]+red[2]+red[3]+red[4]+red[5]) * (1.0f/CSS);
  float d2 = b - mu2;
  float q2 = waveReduceSum(d2*d2);
  __syncthreads();
  if(lane==0) red[wid]=q2;
  __syncthreads();
  float var2 = (red[0]+red[1]+red[2]+red[3]+red[4]+red[5]) * (1.0f/CSS);
  float r2 = rsqrtf(var2 + 1e-5f);
  scb[(size_t)row*CSS + t] = f2bf(d2*r2*w[t]);
}

// ---------------- qkvg GEMM (128x128 tile): C(2048 x 3072) bf16 ----------------
__global__ __launch_bounds__(256) void gemm_qkvg(const unsigned short* __restrict__ A,
    const unsigned short* __restrict__ Bt, const float* __restrict__ bias,
    unsigned short* __restrict__ C){
  __shared__ unsigned short As[128*32];
  __shared__ unsigned short Bs[128*32];
  const int tid = threadIdx.x;
  const int w = tid>>6, lane = tid&63;
  const int ln15 = lane&15, hi = lane>>4;
  const int wm = w&1, wn = w>>1;
  const int m0 = blockIdx.y*128, n0 = blockIdx.x*128;
  const int lrow = lane>>2, lk = (lane&3)*8;
  const int K = 768, NC = 3072;

  f32x4 z = {0.f,0.f,0.f,0.f};
  f32x4 acc[4][4];
  #pragma unroll
  for(int i=0;i<4;i++)
    #pragma unroll
    for(int j=0;j<4;j++) acc[i][j] = z;

  for(int k0=0;k0<K;k0+=32){
    const unsigned short* ga = A + (size_t)(m0 + w*32 + lrow)*K + k0 + lk;
    const unsigned short* gb = Bt + (size_t)(n0 + w*32 + lrow)*K + k0 + lk;
    async_copy16(ga,          &As[w*1024]);
    async_copy16(ga + 16*K,   &As[w*1024 + 512]);
    async_copy16(gb,          &Bs[w*1024]);
    async_copy16(gb + 16*K,   &Bs[w*1024 + 512]);
    __syncthreads();
    bf16x8 af[4], bfr[4];
    #pragma unroll
    for(int i=0;i<4;i++) af[i]  = *(const bf16x8*)&As[(wm*64 + i*16 + ln15)*32 + hi*8];
    #pragma unroll
    for(int j=0;j<4;j++) bfr[j] = *(const bf16x8*)&Bs[(wn*64 + j*16 + ln15)*32 + hi*8];
    #pragma unroll
    for(int i=0;i<4;i++)
      #pragma unroll
      for(int j=0;j<4;j++)
        acc[i][j] = MFMA16(af[i], bfr[j], acc[i][j]);
    __syncthreads();
  }

  #pragma unroll
  for(int i=0;i<4;i++)
    #pragma unroll
    for(int j=0;j<4;j++)
      #pragma unroll
      for(int r=0;r<4;r++){
        int gm = m0 + wm*64 + i*16 + hi*4 + r;
        int gn = n0 + wn*64 + j*16 + ln15;
        float v = acc[i][j][r];
        if(gn < 768) v += bias[gn];
        if(gn >= 2304) v = 1.0f/(1.0f + __expf(-v));
        C[(size_t)gm*NC + gn] = f2bf(v);
      }
}

// ---------------- AdaLN triple-GEMM (64x64 tile, 384 blocks) ----------------
// xa = sigmoid(sc@Ws+bs)*xn + sc@Wb ; azc = sigmoid(sc@Wz + zb)
__global__ __launch_bounds__(256) void adaln3(const unsigned short* __restrict__ A,
    const unsigned short* __restrict__ B1, const unsigned short* __restrict__ B2,
    const unsigned short* __restrict__ B3, const float* __restrict__ bs,
    const float* __restrict__ zb, const float* __restrict__ xn,
    unsigned short* __restrict__ xa, float* __restrict__ azc){
  __shared__ unsigned short As[64*32];
  __shared__ unsigned short Bs1[64*32];
  __shared__ unsigned short Bs2[64*32];
  __shared__ unsigned short Bs3[64*32];
  const int tid = threadIdx.x;
  const int w = tid>>6, lane = tid&63;
  const int ln15 = lane&15, hi = lane>>4;
  const int wm = w&1, wn = w>>1;
  const int m0 = blockIdx.y*64, n0 = blockIdx.x*64;
  const int lrow = tid>>2, lk = (tid&3)*8;   // block-wide staging map
  const int K = CSS;

  f32x4 z = {0.f,0.f,0.f,0.f};
  f32x4 acc1[2][2], acc2[2][2], acc3[2][2];
  #pragma unroll
  for(int i=0;i<2;i++)
    #pragma unroll
    for(int j=0;j<2;j++){ acc1[i][j]=z; acc2[i][j]=z; acc3[i][j]=z; }

  for(int k0=0;k0<K;k0+=32){
    async_copy16(A  + (size_t)(m0+lrow)*K + k0 + lk, &As [w*512]);
    async_copy16(B1 + (size_t)(n0+lrow)*K + k0 + lk, &Bs1[w*512]);
    async_copy16(B2 + (size_t)(n0+lrow)*K + k0 + lk, &Bs2[w*512]);
    async_copy16(B3 + (size_t)(n0+lrow)*K + k0 + lk, &Bs3[w*512]);
    __syncthreads();
    bf16x8 af[2], b1f[2], b2f[2], b3f[2];
    #pragma unroll
    for(int i=0;i<2;i++) af[i]  = *(const bf16x8*)&As[(wm*32 + i*16 + ln15)*32 + hi*8];
    #pragma unroll
    for(int j=0;j<2;j++){
      b1f[j] = *(const bf16x8*)&Bs1[(wn*32 + j*16 + ln15)*32 + hi*8];
      b2f[j] = *(const bf16x8*)&Bs2[(wn*32 + j*16 + ln15)*32 + hi*8];
      b3f[j] = *(const bf16x8*)&Bs3[(wn*32 + j*16 + ln15)*32 + hi*8];
    }
    #pragma unroll
    for(int i=0;i<2;i++)
      #pragma unroll
      for(int j=0;j<2;j++){
        acc1[i][j] = MFMA16(af[i], b1f[j], acc1[i][j]);
        acc2[i][j] = MFMA16(af[i], b2f[j], acc2[i][j]);
        acc3[i][j] = MFMA16(af[i], b3f[j], acc3[i][j]);
      }
    __syncthreads();
  }

  #pragma unroll
  for(int i=0;i<2;i++)
    #pragma unroll
    for(int j=0;j<2;j++)
      #pragma unroll
      for(int r=0;r<4;r++){
        int gm = m0 + wm*32 + i*16 + hi*4 + r;
        int gn = n0 + wn*32 + j*16 + ln15;
        float g = 1.0f/(1.0f + __expf(-(acc1[i][j][r] + bs[gn])));
        float v = g * xn[(size_t)gm*CXX + gn] + acc2[i][j][r];
        xa[(size_t)gm*CXX + gn] = f2bf(v);
        azc[(size_t)gm*CXX + gn] = 1.0f/(1.0f + __expf(-(acc3[i][j][r] + zb[gn])));
      }
}

// ---------------- out GEMM (64x64 tile): out = (wag @ out_w) * azc, fp32 ----------
__global__ __launch_bounds__(256) void gemm_out(const unsigned short* __restrict__ A,
    const unsigned short* __restrict__ Bt, const float* __restrict__ mul,
    float* __restrict__ C){
  __shared__ unsigned short As[64*32];
  __shared__ unsigned short Bs[64*32];
  const int tid = threadIdx.x;
  const int w = tid>>6, lane = tid&63;
  const int ln15 = lane&15, hi = lane>>4;
  const int wm = w&1, wn = w>>1;
  const int m0 = blockIdx.y*64, n0 = blockIdx.x*64;
  const int lrow = tid>>2, lk = (tid&3)*8;
  const int K = 768;

  f32x4 z = {0.f,0.f,0.f,0.f};
  f32x4 acc[2][2];
  #pragma unroll
  for(int i=0;i<2;i++)
    #pragma unroll
    for(int j=0;j<2;j++) acc[i][j]=z;

  for(int k0=0;k0<K;k0+=32){
    async_copy16(A  + (size_t)(m0+lrow)*K + k0 + lk, &As[w*512]);
    async_copy16(Bt + (size_t)(n0+lrow)*K + k0 + lk, &Bs[w*512]);
    __syncthreads();
    bf16x8 af[2], bfr[2];
    #pragma unroll
    for(int i=0;i<2;i++) af[i]  = *(const bf16x8*)&As[(wm*32 + i*16 + ln15)*32 + hi*8];
    #pragma unroll
    for(int j=0;j<2;j++) bfr[j] = *(const bf16x8*)&Bs[(wn*32 + j*16 + ln15)*32 + hi*8];
    #pragma unroll
    for(int i=0;i<2;i++)
      #pragma unroll
      for(int j=0;j<2;j++)
        acc[i][j] = MFMA16(af[i], bfr[j], acc[i][j]);
    __syncthreads();
  }

  #pragma unroll
  for(int i=0;i<2;i++)
    #pragma unroll
    for(int j=0;j<2;j++)
      #pragma unroll
      for(int r=0;r<4;r++){
        int gm = m0 + wm*32 + i*16 + hi*4 + r;
        int gn = n0 + wn*32 + j*16 + ln15;
        C[(size_t)gm*CXX + gn] = acc[i][j][r] * mul[(size_t)gm*CXX + gn];
      }
}

// ---------------- MFMA flash attention, software-pipelined ----------------
__global__ __launch_bounds__(256) void attn_mfma(const unsigned short* __restrict__ qkvg,
    const float* __restrict__ pair, const int* __restrict__ mask,
    unsigned short* __restrict__ wag){
  const int h = blockIdx.y;
  const int q0 = blockIdx.x*64;
  const int tid = threadIdx.x;
  const int w = tid>>6, lane = tid&63;
  const int ln15 = lane&15, hi = lane>>4;

  __shared__ unsigned short Qs[64*72];
  __shared__ unsigned short Ks[64*72];
  __shared__ unsigned short VsT[48*72];
  __shared__ unsigned short Ps[4][16*72];

  for(int idx=tid; idx<64*16; idx+=256){
    int row = idx>>4, d = 48 + (idx&15);
    Qs[row*72 + d] = 0;
    Ks[row*72 + d] = 0;
  }
  for(int idx=tid; idx<64*12; idx+=256){
    int qr = idx&63, d0 = (idx>>6)*4;
    ushort4 v = *(const ushort4*)&qkvg[(size_t)(q0+qr)*3072 + h*DHH + d0];
    *(ushort4*)&Qs[qr*72 + d0] = v;
  }
  __syncthreads();

  bf16x8 aq0 = *(const bf16x8*)&Qs[(w*16+ln15)*72 + hi*8];
  bf16x8 aq1 = *(const bf16x8*)&Qs[(w*16+ln15)*72 + 32 + hi*8];

  f32x4 z = {0.f,0.f,0.f,0.f};
  f32x4 oacc[3] = {z,z,z};
  float mold[4] = {-1e30f,-1e30f,-1e30f,-1e30f};
  float l[4] = {0.f,0.f,0.f,0.f};
  const float scale = 0.14433756729740643f;
  const int qrb = w*16 + hi*4;

  // ---- prefetch tile 0 into registers ----
  ushort4 kreg[3], vreg[3];
  int mreg[4];
  float preg[4][4];
  {
    #pragma unroll
    for(int it=0;it<3;it++){
      int idx = tid + it*256;
      int key = idx&63, d0 = (idx>>6)*4;
      kreg[it] = *(const ushort4*)&qkvg[(size_t)key*3072 +  768 + h*DHH + d0];
      vreg[it] = *(const ushort4*)&qkvg[(size_t)key*3072 + 1536 + h*DHH + d0];
    }
    #pragma unroll
    for(int jt=0;jt<4;jt++) mreg[jt] = mask[jt*16 + ln15];
    const float* pb = pair + ((size_t)h*NN + (size_t)(q0+qrb))*NN + ln15;
    #pragma unroll
    for(int r=0;r<4;r++)
      #pragma unroll
      for(int jt=0;jt<4;jt++)
        preg[jt][r] = pb[(size_t)r*NN + jt*16];
  }

  for(int kt=0; kt<NN/64; ++kt){
    __syncthreads();    // previous tile's LDS reads complete
    // write prefetched K/V registers to LDS
    #pragma unroll
    for(int it=0;it<3;it++){
      int idx = tid + it*256;
      int key = idx&63, d0 = (idx>>6)*4;
      ushort4 kv = kreg[it];
      *(ushort4*)&Ks[key*72 + d0] = kv;
      ushort4 vv = vreg[it];
      VsT[(d0+0)*72 + key] = vv.x;
      VsT[(d0+1)*72 + key] = vv.y;
      VsT[(d0+2)*72 + key] = vv.z;
      VsT[(d0+3)*72 + key] = vv.w;
    }
    __syncthreads();

    // snapshot current pair/mask, then issue next-tile loads
    float pc[4][4]; int mc[4];
    #pragma unroll
    for(int jt=0;jt<4;jt++){
      mc[jt] = mreg[jt];
      #pragma unroll
      for(int r=0;r<4;r++) pc[jt][r] = preg[jt][r];
    }
    {
      int k0n = (kt < NN/64 - 1) ? (kt+1)*64 : 0;
      #pragma unroll
      for(int it=0;it<3;it++){
        int idx = tid + it*256;
        int key = idx&63, d0 = (idx>>6)*4;
        kreg[it] = *(const ushort4*)&qkvg[(size_t)(k0n+key)*3072 +  768 + h*DHH + d0];
        vreg[it] = *(const ushort4*)&qkvg[(size_t)(k0n+key)*3072 + 1536 + h*DHH + d0];
      }
      #pragma unroll
      for(int jt=0;jt<4;jt++) mreg[jt] = mask[k0n + jt*16 + ln15];
      const float* pb = pair + ((size_t)h*NN + (size_t)(q0+qrb))*NN + k0n + ln15;
      #pragma unroll
      for(int r=0;r<4;r++)
        #pragma unroll
        for(int jt=0;jt<4;jt++)
          preg[jt][r] = pb[(size_t)r*NN + jt*16];
    }

    // S = Q K^T
    f32x4 sreg[4];
    #pragma unroll
    for(int jt=0;jt<4;jt++){
      bf16x8 bk0 = *(const bf16x8*)&Ks[(jt*16+ln15)*72 + hi*8];
      bf16x8 bk1 = *(const bf16x8*)&Ks[(jt*16+ln15)*72 + 32 + hi*8];
      f32x4 s = z;
      s = MFMA16(aq0, bk0, s);
      s = MFMA16(aq1, bk1, s);
      sreg[jt] = s;
    }

    float sv[4][4];
    #pragma unroll
    for(int jt=0;jt<4;jt++)
      #pragma unroll
      for(int r=0;r<4;r++)
        sv[jt][r] = mc[jt] ? sreg[jt][r]*scale + pc[jt][r] : -1e9f;

    // online softmax
    float mr[4], al[4], rs[4];
    #pragma unroll
    for(int r=0;r<4;r++)
      mr[r] = fmaxf(fmaxf(sv[0][r],sv[1][r]), fmaxf(sv[2][r],sv[3][r]));
    #pragma unroll
    for(int o=1;o<16;o<<=1)
      #pragma unroll
      for(int r=0;r<4;r++) mr[r] = fmaxf(mr[r], __shfl_xor(mr[r],o));
    #pragma unroll
    for(int r=0;r<4;r++){
      float mn = fmaxf(mold[r], mr[r]);
      al[r] = __expf(mold[r] - mn);
      mold[r] = mn;
    }
    float pv[4][4];
    #pragma unroll
    for(int jt=0;jt<4;jt++)
      #pragma unroll
      for(int r=0;r<4;r++)
        pv[jt][r] = __expf(sv[jt][r] - mold[r]);
    #pragma unroll
    for(int r=0;r<4;r++) rs[r] = pv[0][r]+pv[1][r]+pv[2][r]+pv[3][r];
    #pragma unroll
    for(int o=1;o<16;o<<=1)
      #pragma unroll
      for(int r=0;r<4;r++) rs[r] += __shfl_xor(rs[r],o);
    #pragma unroll
    for(int r=0;r<4;r++) l[r] = l[r]*al[r] + rs[r];

    // P -> per-wave LDS (A-frag layout round trip)
    #pragma unroll
    for(int jt=0;jt<4;jt++)
      #pragma unroll
      for(int r=0;r<4;r++)
        Ps[w][(hi*4+r)*72 + jt*16 + ln15] = f2bf(pv[jt][r]);
    __asm__ volatile("s_waitcnt lgkmcnt(0)" ::: "memory");

    #pragma unroll
    for(int dt=0;dt<3;dt++)
      #pragma unroll
      for(int r=0;r<4;r++) oacc[dt][r] *= al[r];

    bf16x8 ap0 = *(const bf16x8*)&Ps[w][ln15*72 + hi*8];
    bf16x8 ap1 = *(const bf16x8*)&Ps[w][ln15*72 + 32 + hi*8];
    #pragma unroll
    for(int dt=0;dt<3;dt++){
      bf16x8 bv0 = *(const bf16x8*)&VsT[(dt*16+ln15)*72 + hi*8];
      bf16x8 bv1 = *(const bf16x8*)&VsT[(dt*16+ln15)*72 + 32 + hi*8];
      oacc[dt] = MFMA16(ap0, bv0, oacc[dt]);
      oacc[dt] = MFMA16(ap1, bv1, oacc[dt]);
    }
  }

  #pragma unroll
  for(int r=0;r<4;r++){
    float linv = 1.0f / l[r];
    int qrow = q0 + qrb + r;
    #pragma unroll
    for(int dt=0;dt<3;dt++){
      int col = h*DHH + dt*16 + ln15;
      float g = bf2f(qkvg[(size_t)qrow*3072 + 2304 + col]);
      float o = oacc[dt][r] * linv * g;
      wag[(size_t)qrow*CXX + col] = f2bf(o);
    }
  }
}

extern "C" void kernel_launch(void* const* d_in, const int* in_sizes, int n_in,
                              void* d_out, int out_size, void* d_ws, size_t ws_size,
                              hipStream_t stream) {
  const float* x           = (const float*)d_in[0];
  const int*   mask        = (const int*)  d_in[1];
  const float* pair        = (const float*)d_in[2];
  const float* single_cond = (const float*)d_in[3];
  const float* ln_sc_w     = (const float*)d_in[4];
  const float* sc_scale_w  = (const float*)d_in[5];
  const float* sc_scale_b  = (const float*)d_in[6];
  const float* sc_bias_w   = (const float*)d_in[7];
  const float* q_w         = (const float*)d_in[8];
  const float* q_b         = (const float*)d_in[9];
  const float* k_w         = (const float*)d_in[10];
  const float* v_w         = (const float*)d_in[11];
  const float* gate_w      = (const float*)d_in[12];
  const float* out_w       = (const float*)d_in[13];
  const float* azc_w       = (const float*)d_in[14];
  const float* azc_b       = (const float*)d_in[15];
  float* out = (float*)d_out;

  unsigned short* p = (unsigned short*)d_ws;
  unsigned short* Wt_scale = p;  p += 768*384;
  unsigned short* Wt_bias  = p;  p += 768*384;
  unsigned short* Wt_azc   = p;  p += 768*384;
  unsigned short* Wt_out   = p;  p += 768*768;
  unsigned short* Wt_qkvg  = p;  p += (size_t)3072*768;
  unsigned short* scb      = p;  p += 2048*384;
  unsigned short* xa       = p;  p += 2048*768;
  unsigned short* qkvg     = p;  p += (size_t)2048*3072;
  unsigned short* wag      = p;  p += 2048*768;
  float* fp = (float*)p;
  float* xn  = fp; fp += (size_t)2048*768;
  float* azc = fp;

  transpose_all<<<dim3(24,24,8), 256, 0, stream>>>(
      sc_scale_w, sc_bias_w, azc_w, q_w, k_w, v_w, gate_w, out_w,
      Wt_scale, Wt_bias, Wt_azc, Wt_qkvg, Wt_out);

  ln_fused<<<NN, 384, 0, stream>>>(x, single_cond, ln_sc_w, xn, scb);

  adaln3<<<dim3(12,32), 256, 0, stream>>>(scb, Wt_scale, Wt_bias, Wt_azc,
                                          sc_scale_b, azc_b, xn, xa, azc);

  gemm_qkvg<<<dim3(24,16), 256, 0, stream>>>(xa, Wt_qkvg, q_b, qkvg);

  attn_mfma<<<dim3(32,16), 256, 0, stream>>>(qkvg, pair, mask, wag);

  gemm_out<<<dim3(12,32), 256, 0, stream>>>(wag, Wt_out, azc, out);
}